// Round 1
// baseline (11009.100 us; speedup 1.0000x reference)
//
#include <hip/hip_runtime.h>
#include <hip/hip_cooperative_groups.h>

namespace cg = cooperative_groups;

typedef short short8 __attribute__((ext_vector_type(8)));
typedef float f32x4 __attribute__((ext_vector_type(4)));
typedef unsigned short us4 __attribute__((ext_vector_type(4)));
typedef unsigned short ushort_t;

#define SQ 512
#define BA 64
#define HD 1024

// ---------- bf16 helpers (round-to-nearest-even; no NaN inputs here) ----------
__device__ __forceinline__ unsigned short f2bf(float f) {
    unsigned u = __float_as_uint(f);
    u += 0x7fffu + ((u >> 16) & 1u);
    return (unsigned short)(u >> 16);
}
__device__ __forceinline__ float bf2f(unsigned short h) {
    return __uint_as_float(((unsigned)h) << 16);
}

// =====================================================================
// Phase A: xw[s*B+b][h] = x[s,b,:] . W_ih[h,:] + (b_ih[h]+b_hh[h])
// M=32768, N=1024, K=1024. Split-bf16 (hi/lo), 3 MFMA products, fp32 out.
// Tile 128x128, BK=32, 256 threads = 4 waves (2x2 of 64x64).
// =====================================================================
__global__ void __launch_bounds__(256) xw_gemm(
    const float* __restrict__ x, const float* __restrict__ Wih,
    const float* __restrict__ bih, const float* __restrict__ bhh,
    float* __restrict__ out)
{
    // +8 ushort pad -> ds_read_b128 per 16-lane column group is 2-way (free)
    __shared__ unsigned short Ahi[128][40];
    __shared__ unsigned short Alo[128][40];
    __shared__ unsigned short Bhi[128][40];
    __shared__ unsigned short Blo[128][40];

    const int tid  = threadIdx.x;
    const int lane = tid & 63, wid = tid >> 6;
    const int bx = blockIdx.x, by = blockIdx.y;
    const int wm = (wid & 1) * 64, wn = (wid >> 1) * 64;
    const int rf = lane & 15, bq = lane >> 4, kf = bq * 8;

    f32x4 acc[4][4] = {};

    const int srow = tid >> 3;        // 0..31
    const int scol = (tid & 7) * 4;   // 0..28
    const float* aBase = x   + (size_t)(bx * 128 + srow) * HD + scol;
    const float* bBase = Wih + (size_t)(by * 128 + srow) * HD + scol;

    for (int kc = 0; kc < 32; ++kc) {
        __syncthreads();
        const int ko = kc * 32;
#pragma unroll
        for (int i = 0; i < 4; ++i) {
            const int r = srow + i * 32;
            float4 av = *(const float4*)(aBase + (size_t)(i * 32) * HD + ko);
            float4 bv = *(const float4*)(bBase + (size_t)(i * 32) * HD + ko);
            us4 ah, al, bh, bl;
            ah.x = f2bf(av.x); al.x = f2bf(av.x - bf2f(ah.x));
            ah.y = f2bf(av.y); al.y = f2bf(av.y - bf2f(ah.y));
            ah.z = f2bf(av.z); al.z = f2bf(av.z - bf2f(ah.z));
            ah.w = f2bf(av.w); al.w = f2bf(av.w - bf2f(ah.w));
            bh.x = f2bf(bv.x); bl.x = f2bf(bv.x - bf2f(bh.x));
            bh.y = f2bf(bv.y); bl.y = f2bf(bv.y - bf2f(bh.y));
            bh.z = f2bf(bv.z); bl.z = f2bf(bv.z - bf2f(bh.z));
            bh.w = f2bf(bv.w); bl.w = f2bf(bv.w - bf2f(bh.w));
            *(us4*)&Ahi[r][scol] = ah;
            *(us4*)&Alo[r][scol] = al;
            *(us4*)&Bhi[r][scol] = bh;
            *(us4*)&Blo[r][scol] = bl;
        }
        __syncthreads();

        short8 afh[4], afl[4], bfh[4], bfl[4];
#pragma unroll
        for (int i = 0; i < 4; ++i) {
            afh[i] = *(const short8*)&Ahi[wm + 16 * i + rf][kf];
            afl[i] = *(const short8*)&Alo[wm + 16 * i + rf][kf];
            bfh[i] = *(const short8*)&Bhi[wn + 16 * i + rf][kf];
            bfl[i] = *(const short8*)&Blo[wn + 16 * i + rf][kf];
        }
#pragma unroll
        for (int i = 0; i < 4; ++i)
#pragma unroll
            for (int j = 0; j < 4; ++j) {
                acc[i][j] = __builtin_amdgcn_mfma_f32_16x16x32_bf16(afh[i], bfh[j], acc[i][j], 0, 0, 0);
                acc[i][j] = __builtin_amdgcn_mfma_f32_16x16x32_bf16(afh[i], bfl[j], acc[i][j], 0, 0, 0);
                acc[i][j] = __builtin_amdgcn_mfma_f32_16x16x32_bf16(afl[i], bfh[j], acc[i][j], 0, 0, 0);
            }
    }

    // epilogue: D[m=(lane>>4)*4+r][n=lane&15]  (m89-verified C/D layout)
#pragma unroll
    for (int j = 0; j < 4; ++j) {
        const int col = by * 128 + wn + 16 * j + rf;
        const float bias = bih[col] + bhh[col];
#pragma unroll
        for (int i = 0; i < 4; ++i) {
            const int row0 = bx * 128 + wm + 16 * i + bq * 4;
#pragma unroll
            for (int r = 0; r < 4; ++r)
                out[(size_t)(row0 + r) * HD + col] = acc[i][j][r] + bias;
        }
    }
}

// =====================================================================
// Phase B: sequential recurrence. 64 cooperative WGs x 256 thr (4 waves).
// WG j owns H-slice [16*j, 16*j+16); W_hh slice resident in LDS (split bf16).
// h ping-pong in d_ws as split bf16; one grid.sync() per step.
// io = d_out: holds xw on entry, h (the output) on exit, overwritten in place.
// =====================================================================
__global__ void __launch_bounds__(256) rnn_recurrence(
    const float* __restrict__ Whh,
    float* __restrict__ io,
    float* __restrict__ hn,
    unsigned short* __restrict__ hbuf)
{
    __shared__ unsigned short Whi[16][1032];   // pad +8: 2-way-only LDS conflicts
    __shared__ unsigned short Wlo[16][1032];

    const int tid = threadIdx.x;
    const int h0  = blockIdx.x * 16;

    // one-time: load + split-convert W_hh slice into LDS
    for (int i = tid; i < 16 * 1024; i += 256) {
        const int r = i >> 10, c = i & 1023;
        const float w = Whh[(size_t)(h0 + r) * HD + c];
        const unsigned short hi = f2bf(w);
        Whi[r][c] = hi;
        Wlo[r][c] = f2bf(w - bf2f(hi));
    }
    __syncthreads();

    const int lane = tid & 63, wid = tid >> 6;
    const int rf = lane & 15, bq = lane >> 4, kf = bq * 8;

    unsigned short* Hh0 = hbuf;
    unsigned short* Hl0 = hbuf + 1 * BA * HD;
    unsigned short* Hh1 = hbuf + 2 * BA * HD;
    unsigned short* Hl1 = hbuf + 3 * BA * HD;

    cg::grid_group grid = cg::this_grid();

    // ---- t = 0: h_0 = 0 -> h = tanh(xw_0) ----
#pragma unroll
    for (int r = 0; r < 4; ++r) {
        const int b = wid * 16 + bq * 4 + r;
        const size_t o = (size_t)b * HD + (h0 + rf);
        const float v = tanhf(io[o]);
        io[o] = v;
        const unsigned short hi = f2bf(v);
        Hh0[o] = hi;
        Hl0[o] = f2bf(v - bf2f(hi));
    }

    // ---- t = 1 .. 511 ----
    for (int t = 1; t < SQ; ++t) {
        grid.sync();   // step t-1 writes visible to all (release/acquire)

        const unsigned short* Ph = (t & 1) ? Hh0 : Hh1;   // read (t-1)&1
        const unsigned short* Pl = (t & 1) ? Hl0 : Hl1;
        unsigned short* Nh = (t & 1) ? Hh1 : Hh0;         // write t&1
        unsigned short* Nl = (t & 1) ? Hl1 : Hl0;

        const int ab = wid * 16 + rf;                      // A-frag row = batch
        const unsigned short* ah = Ph + (size_t)ab * HD + kf;
        const unsigned short* al = Pl + (size_t)ab * HD + kf;

        f32x4 acc = {};
#pragma unroll 8
        for (int kc = 0; kc < 32; ++kc) {
            short8 Af_h = *(const short8*)(ah + kc * 32);
            short8 Af_l = *(const short8*)(al + kc * 32);
            short8 Bf_h = *(const short8*)&Whi[rf][kc * 32 + kf];
            short8 Bf_l = *(const short8*)&Wlo[rf][kc * 32 + kf];
            acc = __builtin_amdgcn_mfma_f32_16x16x32_bf16(Af_h, Bf_h, acc, 0, 0, 0);
            acc = __builtin_amdgcn_mfma_f32_16x16x32_bf16(Af_h, Bf_l, acc, 0, 0, 0);
            acc = __builtin_amdgcn_mfma_f32_16x16x32_bf16(Af_l, Bf_h, acc, 0, 0, 0);
        }

        float* outT = io + (size_t)t * (BA * HD);
#pragma unroll
        for (int r = 0; r < 4; ++r) {
            const int b = wid * 16 + bq * 4 + r;
            const size_t o = (size_t)b * HD + (h0 + rf);
            const float pre = acc[r] + outT[o];
            const float v = tanhf(pre);
            outT[o] = v;
            const unsigned short hi = f2bf(v);
            Nh[o] = hi;
            Nl[o] = f2bf(v - bf2f(hi));
            if (t == SQ - 1) hn[o] = v;
        }
    }
}

// =====================================================================
extern "C" void kernel_launch(void* const* d_in, const int* in_sizes, int n_in,
                              void* d_out, int out_size, void* d_ws, size_t ws_size,
                              hipStream_t stream) {
    const float* x   = (const float*)d_in[0];
    const float* Wih = (const float*)d_in[1];
    const float* Whh = (const float*)d_in[2];
    const float* bih = (const float*)d_in[3];
    const float* bhh = (const float*)d_in[4];

    float* io = (float*)d_out;                       // [512][64][1024]: xw -> h
    float* hn = io + (size_t)SQ * BA * HD;           // [1][64][1024]
    unsigned short* hbuf = (unsigned short*)d_ws;    // 2 x (hi,lo) x [64][1024], 512 KB

    // Phase A: big GEMM, 2048 WGs
    hipLaunchKernelGGL(xw_gemm, dim3(256, 8), dim3(256), 0, stream,
                       x, Wih, bih, bhh, io);

    // Phase B: cooperative recurrence, 64 WGs
    void* args[] = {(void*)&Whh, (void*)&io, (void*)&hn, (void*)&hbuf};
    hipLaunchCooperativeKernel((void*)rnn_recurrence, dim3(64), dim3(256),
                               args, 0, stream);
}

// Round 2
// 9099.308 us; speedup vs baseline: 1.2099x; 1.2099x over previous
//
#include <hip/hip_runtime.h>
#include <hip/hip_cooperative_groups.h>

typedef short short8 __attribute__((ext_vector_type(8)));
typedef float f32x4 __attribute__((ext_vector_type(4)));
typedef unsigned short us4 __attribute__((ext_vector_type(4)));

#define SQ 512
#define BA 64
#define HD 1024
#define NWG 64

// ---------- bf16 helpers (round-to-nearest-even) ----------
__device__ __forceinline__ unsigned short f2bf(float f) {
    unsigned u = __float_as_uint(f);
    u += 0x7fffu + ((u >> 16) & 1u);
    return (unsigned short)(u >> 16);
}
__device__ __forceinline__ float bf2f(unsigned short h) {
    return __uint_as_float(((unsigned)h) << 16);
}

__device__ __forceinline__ void waitcnt_vm0() {
    asm volatile("s_waitcnt vmcnt(0)" ::: "memory");
}

// agent-scope (LLC-coherent) 16-B fragment load as 2x8-B relaxed atomics
__device__ __forceinline__ short8 ld_frag(const unsigned short* p) {
    const unsigned long long* q = (const unsigned long long*)p;
    unsigned long long a = __hip_atomic_load(q,     __ATOMIC_RELAXED, __HIP_MEMORY_SCOPE_AGENT);
    unsigned long long b = __hip_atomic_load(q + 1, __ATOMIC_RELAXED, __HIP_MEMORY_SCOPE_AGENT);
    union { unsigned long long u[2]; short8 v; } cv;
    cv.u[0] = a; cv.u[1] = b;
    return cv.v;
}

// =====================================================================
// Phase A: xw = x @ W_ih^T + bias. Split-bf16, 3 MFMA products. Unchanged.
// =====================================================================
__global__ void __launch_bounds__(256) xw_gemm(
    const float* __restrict__ x, const float* __restrict__ Wih,
    const float* __restrict__ bih, const float* __restrict__ bhh,
    float* __restrict__ out, unsigned* __restrict__ ctr)
{
    if (blockIdx.x == 0 && blockIdx.y == 0 && threadIdx.x == 0) *ctr = 0u;

    __shared__ unsigned short Ahi[128][40];
    __shared__ unsigned short Alo[128][40];
    __shared__ unsigned short Bhi[128][40];
    __shared__ unsigned short Blo[128][40];

    const int tid  = threadIdx.x;
    const int lane = tid & 63, wid = tid >> 6;
    const int bx = blockIdx.x, by = blockIdx.y;
    const int wm = (wid & 1) * 64, wn = (wid >> 1) * 64;
    const int rf = lane & 15, bq = lane >> 4, kf = bq * 8;

    f32x4 acc[4][4] = {};

    const int srow = tid >> 3;
    const int scol = (tid & 7) * 4;
    const float* aBase = x   + (size_t)(bx * 128 + srow) * HD + scol;
    const float* bBase = Wih + (size_t)(by * 128 + srow) * HD + scol;

    for (int kc = 0; kc < 32; ++kc) {
        __syncthreads();
        const int ko = kc * 32;
#pragma unroll
        for (int i = 0; i < 4; ++i) {
            const int r = srow + i * 32;
            float4 av = *(const float4*)(aBase + (size_t)(i * 32) * HD + ko);
            float4 bv = *(const float4*)(bBase + (size_t)(i * 32) * HD + ko);
            us4 ah, al, bh, bl;
            ah.x = f2bf(av.x); al.x = f2bf(av.x - bf2f(ah.x));
            ah.y = f2bf(av.y); al.y = f2bf(av.y - bf2f(ah.y));
            ah.z = f2bf(av.z); al.z = f2bf(av.z - bf2f(ah.z));
            ah.w = f2bf(av.w); al.w = f2bf(av.w - bf2f(ah.w));
            bh.x = f2bf(bv.x); bl.x = f2bf(bv.x - bf2f(bh.x));
            bh.y = f2bf(bv.y); bl.y = f2bf(bv.y - bf2f(bh.y));
            bh.z = f2bf(bv.z); bl.z = f2bf(bv.z - bf2f(bh.z));
            bh.w = f2bf(bv.w); bl.w = f2bf(bv.w - bf2f(bh.w));
            *(us4*)&Ahi[r][scol] = ah;
            *(us4*)&Alo[r][scol] = al;
            *(us4*)&Bhi[r][scol] = bh;
            *(us4*)&Blo[r][scol] = bl;
        }
        __syncthreads();

        short8 afh[4], afl[4], bfh[4], bfl[4];
#pragma unroll
        for (int i = 0; i < 4; ++i) {
            afh[i] = *(const short8*)&Ahi[wm + 16 * i + rf][kf];
            afl[i] = *(const short8*)&Alo[wm + 16 * i + rf][kf];
            bfh[i] = *(const short8*)&Bhi[wn + 16 * i + rf][kf];
            bfl[i] = *(const short8*)&Blo[wn + 16 * i + rf][kf];
        }
#pragma unroll
        for (int i = 0; i < 4; ++i)
#pragma unroll
            for (int j = 0; j < 4; ++j) {
                acc[i][j] = __builtin_amdgcn_mfma_f32_16x16x32_bf16(afh[i], bfh[j], acc[i][j], 0, 0, 0);
                acc[i][j] = __builtin_amdgcn_mfma_f32_16x16x32_bf16(afh[i], bfl[j], acc[i][j], 0, 0, 0);
                acc[i][j] = __builtin_amdgcn_mfma_f32_16x16x32_bf16(afl[i], bfh[j], acc[i][j], 0, 0, 0);
            }
    }

#pragma unroll
    for (int j = 0; j < 4; ++j) {
        const int col = by * 128 + wn + 16 * j + rf;
        const float bias = bih[col] + bhh[col];
#pragma unroll
        for (int i = 0; i < 4; ++i) {
            const int row0 = bx * 128 + wm + 16 * i + bq * 4;
#pragma unroll
            for (int r = 0; r < 4; ++r)
                out[(size_t)(row0 + r) * HD + col] = acc[i][j][r] + bias;
        }
    }
}

// =====================================================================
// Phase B: recurrence with hand-rolled LLC barrier (no wbl2/inv).
// 64 WGs x 256 thr; WG j owns H cols [16j,16j+16), W slice in LDS (split).
// h ping-pong in d_ws via agent-scope relaxed atomics (LLC-coherent).
// =====================================================================
__global__ void __launch_bounds__(256) rnn_recurrence(
    const float* __restrict__ Whh,
    float* __restrict__ io,
    float* __restrict__ hn,
    unsigned short* __restrict__ hbuf,
    unsigned* __restrict__ ctr)
{
    __shared__ unsigned short Whi[16][1032];
    __shared__ unsigned short Wlo[16][1032];

    const int tid = threadIdx.x;
    const int h0  = blockIdx.x * 16;

    for (int i = tid; i < 16 * 1024; i += 256) {
        const int r = i >> 10, c = i & 1023;
        const float w = Whh[(size_t)(h0 + r) * HD + c];
        const unsigned short hi = f2bf(w);
        Whi[r][c] = hi;
        Wlo[r][c] = f2bf(w - bf2f(hi));
    }
    __syncthreads();

    const int lane = tid & 63, wid = tid >> 6;
    const int rf = lane & 15, bq = lane >> 4, kf = bq * 8;

    unsigned short* Hh0 = hbuf;
    unsigned short* Hl0 = hbuf + 1 * BA * HD;
    unsigned short* Hh1 = hbuf + 2 * BA * HD;
    unsigned short* Hl1 = hbuf + 3 * BA * HD;

    // ---- helper lambda: pack pairs via shfl and store 4-B agent atomics ----
    auto store_h = [&](unsigned short* Nh, unsigned short* Nl,
                       const unsigned hi4[4], const unsigned lo4[4]) {
#pragma unroll
        for (int r = 0; r < 4; ++r) {
            const unsigned oh = __shfl_xor(hi4[r], 1);
            const unsigned ol = __shfl_xor(lo4[r], 1);
            if ((lane & 1) == 0) {
                const int b = wid * 16 + bq * 4 + r;
                const size_t e = ((size_t)b * HD + (h0 + rf)) >> 1;  // uint index
                __hip_atomic_store((unsigned*)Nh + e, (hi4[r] & 0xffffu) | (oh << 16),
                                   __ATOMIC_RELAXED, __HIP_MEMORY_SCOPE_AGENT);
                __hip_atomic_store((unsigned*)Nl + e, (lo4[r] & 0xffffu) | (ol << 16),
                                   __ATOMIC_RELAXED, __HIP_MEMORY_SCOPE_AGENT);
            }
        }
    };

    // ---- t = 0: h = tanh(xw_0) ----
    {
        unsigned hi4[4], lo4[4];
#pragma unroll
        for (int r = 0; r < 4; ++r) {
            const int b = wid * 16 + bq * 4 + r;
            const size_t o = (size_t)b * HD + (h0 + rf);
            const float v = tanhf(io[o]);
            io[o] = v;
            const unsigned short hi = f2bf(v);
            hi4[r] = hi;
            lo4[r] = f2bf(v - bf2f(hi));
        }
        store_h(Hh0, Hl0, hi4, lo4);
    }

    const int ab = wid * 16 + rf;   // A-frag row = batch index for this lane

    for (int t = 1; t < SQ; ++t) {
        // prefetch xw[t] for our slice (plain cached loads; no cross-step race)
        float* outT = io + (size_t)t * (BA * HD);
        float xwv[4];
#pragma unroll
        for (int r = 0; r < 4; ++r)
            xwv[r] = outT[(size_t)(wid * 16 + bq * 4 + r) * HD + (h0 + rf)];

        // ---- barrier: h stores acked at LLC, then arrive + spin ----
        waitcnt_vm0();
        __syncthreads();
        if (tid == 0) {
            __hip_atomic_fetch_add(ctr, 1u, __ATOMIC_RELAXED, __HIP_MEMORY_SCOPE_AGENT);
            const unsigned target = (unsigned)(NWG * t);
            while (__hip_atomic_load(ctr, __ATOMIC_RELAXED, __HIP_MEMORY_SCOPE_AGENT) < target)
                __builtin_amdgcn_s_sleep(1);
        }
        __syncthreads();

        const unsigned short* Ph = (t & 1) ? Hh0 : Hh1;
        const unsigned short* Pl = (t & 1) ? Hl0 : Hl1;
        unsigned short* Nh = (t & 1) ? Hh1 : Hh0;
        unsigned short* Nl = (t & 1) ? Hl1 : Hl0;

        const unsigned short* ah = Ph + (size_t)ab * HD + kf;
        const unsigned short* al = Pl + (size_t)ab * HD + kf;

        f32x4 acc = {};
#pragma unroll 8
        for (int kc = 0; kc < 32; ++kc) {
            short8 Af_h = ld_frag(ah + kc * 32);
            short8 Af_l = ld_frag(al + kc * 32);
            short8 Bf_h = *(const short8*)&Whi[rf][kc * 32 + kf];
            short8 Bf_l = *(const short8*)&Wlo[rf][kc * 32 + kf];
            acc = __builtin_amdgcn_mfma_f32_16x16x32_bf16(Af_h, Bf_h, acc, 0, 0, 0);
            acc = __builtin_amdgcn_mfma_f32_16x16x32_bf16(Af_h, Bf_l, acc, 0, 0, 0);
            acc = __builtin_amdgcn_mfma_f32_16x16x32_bf16(Af_l, Bf_h, acc, 0, 0, 0);
        }

        unsigned hi4[4], lo4[4];
#pragma unroll
        for (int r = 0; r < 4; ++r) {
            const int b = wid * 16 + bq * 4 + r;
            const size_t o = (size_t)b * HD + (h0 + rf);
            const float v = tanhf(acc[r] + xwv[r]);
            outT[o] = v;
            const unsigned short hi = f2bf(v);
            hi4[r] = hi;
            lo4[r] = f2bf(v - bf2f(hi));
            if (t == SQ - 1) hn[o] = v;
        }
        store_h(Nh, Nl, hi4, lo4);
    }
}

// =====================================================================
extern "C" void kernel_launch(void* const* d_in, const int* in_sizes, int n_in,
                              void* d_out, int out_size, void* d_ws, size_t ws_size,
                              hipStream_t stream) {
    const float* x   = (const float*)d_in[0];
    const float* Wih = (const float*)d_in[1];
    const float* Whh = (const float*)d_in[2];
    const float* bih = (const float*)d_in[3];
    const float* bhh = (const float*)d_in[4];

    float* io = (float*)d_out;                       // [512][64][1024]
    float* hn = io + (size_t)SQ * BA * HD;           // [1][64][1024]

    unsigned* ctr = (unsigned*)d_ws;                               // 64-B slot
    unsigned short* hbuf = (unsigned short*)((char*)d_ws + 64);    // 512 KB ping-pong

    hipLaunchKernelGGL(xw_gemm, dim3(256, 8), dim3(256), 0, stream,
                       x, Wih, bih, bhh, io, ctr);

    void* args[] = {(void*)&Whh, (void*)&io, (void*)&hn, (void*)&hbuf, (void*)&ctr};
    hipLaunchCooperativeKernel((void*)rnn_recurrence, dim3(NWG), dim3(256),
                               args, 0, stream);
}

// Round 4
// 5181.980 us; speedup vs baseline: 2.1245x; 1.7560x over previous
//
#include <hip/hip_runtime.h>

typedef short short8 __attribute__((ext_vector_type(8)));
typedef float f32x4 __attribute__((ext_vector_type(4)));
typedef unsigned short us4 __attribute__((ext_vector_type(4)));

#define SQ 512
#define BA 64
#define HD 1024
#define NWG 64
#define NCTR 8
#define CTR_STRIDE 64   // uints between counters (256 B apart)

// ---------- bf16 helpers (round-to-nearest-even) ----------
__device__ __forceinline__ unsigned short f2bf(float f) {
    unsigned u = __float_as_uint(f);
    u += 0x7fffu + ((u >> 16) & 1u);
    return (unsigned short)(u >> 16);
}
__device__ __forceinline__ float bf2f(unsigned short h) {
    return __uint_as_float(((unsigned)h) << 16);
}
__device__ __forceinline__ void waitcnt_vm0() {
    asm volatile("s_waitcnt vmcnt(0)" ::: "memory");
}
// LLC-coherent 16-B fragment load as 2x8-B relaxed agent atomics
__device__ __forceinline__ short8 ld_frag(const unsigned short* p) {
    const unsigned long long* q = (const unsigned long long*)p;
    unsigned long long a = __hip_atomic_load(q,     __ATOMIC_RELAXED, __HIP_MEMORY_SCOPE_AGENT);
    unsigned long long b = __hip_atomic_load(q + 1, __ATOMIC_RELAXED, __HIP_MEMORY_SCOPE_AGENT);
    union { unsigned long long u[2]; short8 v; } cv;
    cv.u[0] = a; cv.u[1] = b;
    return cv.v;
}

// =====================================================================
// Phase A: xw = x @ W_ih^T + bias. Split-bf16, 3 MFMA products.
// ALSO zero-inits the 8 barrier counters (BUGFIX: block has 256 threads,
// counters live at strided slots 0,64,...,448 — threads 0..7 now zero
// exactly the 8 slots instead of a contiguous 512-uint range).
// =====================================================================
__global__ void __launch_bounds__(256) xw_gemm(
    const float* __restrict__ x, const float* __restrict__ Wih,
    const float* __restrict__ bih, const float* __restrict__ bhh,
    float* __restrict__ out, unsigned* __restrict__ ctr)
{
    if (blockIdx.x == 0 && blockIdx.y == 0 && threadIdx.x < NCTR)
        ctr[threadIdx.x * CTR_STRIDE] = 0u;

    __shared__ unsigned short Ahi[128][40];
    __shared__ unsigned short Alo[128][40];
    __shared__ unsigned short Bhi[128][40];
    __shared__ unsigned short Blo[128][40];

    const int tid  = threadIdx.x;
    const int lane = tid & 63, wid = tid >> 6;
    const int bx = blockIdx.x, by = blockIdx.y;
    const int wm = (wid & 1) * 64, wn = (wid >> 1) * 64;
    const int rf = lane & 15, bq = lane >> 4, kf = bq * 8;

    f32x4 acc[4][4] = {};

    const int srow = tid >> 3;
    const int scol = (tid & 7) * 4;
    const float* aBase = x   + (size_t)(bx * 128 + srow) * HD + scol;
    const float* bBase = Wih + (size_t)(by * 128 + srow) * HD + scol;

    for (int kc = 0; kc < 32; ++kc) {
        __syncthreads();
        const int ko = kc * 32;
#pragma unroll
        for (int i = 0; i < 4; ++i) {
            const int r = srow + i * 32;
            float4 av = *(const float4*)(aBase + (size_t)(i * 32) * HD + ko);
            float4 bv = *(const float4*)(bBase + (size_t)(i * 32) * HD + ko);
            us4 ah, al, bh, bl;
            ah.x = f2bf(av.x); al.x = f2bf(av.x - bf2f(ah.x));
            ah.y = f2bf(av.y); al.y = f2bf(av.y - bf2f(ah.y));
            ah.z = f2bf(av.z); al.z = f2bf(av.z - bf2f(ah.z));
            ah.w = f2bf(av.w); al.w = f2bf(av.w - bf2f(ah.w));
            bh.x = f2bf(bv.x); bl.x = f2bf(bv.x - bf2f(bh.x));
            bh.y = f2bf(bv.y); bl.y = f2bf(bv.y - bf2f(bh.y));
            bh.z = f2bf(bv.z); bl.z = f2bf(bv.z - bf2f(bh.z));
            bh.w = f2bf(bv.w); bl.w = f2bf(bv.w - bf2f(bh.w));
            *(us4*)&Ahi[r][scol] = ah;
            *(us4*)&Alo[r][scol] = al;
            *(us4*)&Bhi[r][scol] = bh;
            *(us4*)&Blo[r][scol] = bl;
        }
        __syncthreads();

        short8 afh[4], afl[4], bfh[4], bfl[4];
#pragma unroll
        for (int i = 0; i < 4; ++i) {
            afh[i] = *(const short8*)&Ahi[wm + 16 * i + rf][kf];
            afl[i] = *(const short8*)&Alo[wm + 16 * i + rf][kf];
            bfh[i] = *(const short8*)&Bhi[wn + 16 * i + rf][kf];
            bfl[i] = *(const short8*)&Blo[wn + 16 * i + rf][kf];
        }
#pragma unroll
        for (int i = 0; i < 4; ++i)
#pragma unroll
            for (int j = 0; j < 4; ++j) {
                acc[i][j] = __builtin_amdgcn_mfma_f32_16x16x32_bf16(afh[i], bfh[j], acc[i][j], 0, 0, 0);
                acc[i][j] = __builtin_amdgcn_mfma_f32_16x16x32_bf16(afh[i], bfl[j], acc[i][j], 0, 0, 0);
                acc[i][j] = __builtin_amdgcn_mfma_f32_16x16x32_bf16(afl[i], bfh[j], acc[i][j], 0, 0, 0);
            }
    }

#pragma unroll
    for (int j = 0; j < 4; ++j) {
        const int col = by * 128 + wn + 16 * j + rf;
        const float bias = bih[col] + bhh[col];
#pragma unroll
        for (int i = 0; i < 4; ++i) {
            const int row0 = bx * 128 + wm + 16 * i + bq * 4;
#pragma unroll
            for (int r = 0; r < 4; ++r)
                out[(size_t)(row0 + r) * HD + col] = acc[i][j][r] + bias;
        }
    }
}

// =====================================================================
// Phase B: recurrence. h stored as SINGLE bf16 (W keeps hi/lo split).
// Distributed 8-line barrier; io stores + xw prefetch off critical path.
// =====================================================================
__global__ void __launch_bounds__(256) rnn_recurrence(
    const float* __restrict__ Whh,
    float* __restrict__ io,
    float* __restrict__ hn,
    unsigned short* __restrict__ hbuf,
    unsigned* __restrict__ ctr)
{
    __shared__ unsigned short Whi[16][1032];
    __shared__ unsigned short Wlo[16][1032];

    const int tid = threadIdx.x;
    const int h0  = blockIdx.x * 16;

    for (int i = tid; i < 16 * 1024; i += 256) {
        const int r = i >> 10, c = i & 1023;
        const float w = Whh[(size_t)(h0 + r) * HD + c];
        const unsigned short hi = f2bf(w);
        Whi[r][c] = hi;
        Wlo[r][c] = f2bf(w - bf2f(hi));
    }
    __syncthreads();

    const int lane = tid & 63, wid = tid >> 6;
    const int rf = lane & 15, bq = lane >> 4, kf = bq * 8;

    unsigned short* H0 = hbuf;             // buffer parity = producing step & 1
    unsigned short* H1 = hbuf + BA * HD;

    const int bslot = (blockIdx.x & (NCTR - 1)) * CTR_STRIDE;
    const int brow  = wid * 16 + bq * 4;   // first of 4 batch rows this lane owns
    const int col   = h0 + rf;

    float v[4];
    unsigned hi4[4];

    // ---- t = 0: h = tanh(xw_0); store to H0 (io[0] stored later, off path) ----
#pragma unroll
    for (int r = 0; r < 4; ++r) {
        v[r] = tanhf(io[(size_t)(brow + r) * HD + col]);
        hi4[r] = f2bf(v[r]);
    }
#pragma unroll
    for (int r = 0; r < 4; ++r) {
        const unsigned oh = __shfl_xor(hi4[r], 1);
        if ((lane & 1) == 0) {
            const size_t e = ((size_t)(brow + r) * HD + col) >> 1;
            __hip_atomic_store((unsigned*)H0 + e, (hi4[r] & 0xffffu) | (oh << 16),
                               __ATOMIC_RELAXED, __HIP_MEMORY_SCOPE_AGENT);
        }
    }

    // prefetch xw[1]
    float xwv[4];
#pragma unroll
    for (int r = 0; r < 4; ++r)
        xwv[r] = io[(size_t)(BA * HD) + (size_t)(brow + r) * HD + col];

    const int ab = wid * 16 + rf;          // A-frag row (batch) for MFMA

    for (int t = 1; t < SQ; ++t) {
        // drain h stores, then arrive
        waitcnt_vm0();
        __syncthreads();
        if (tid == 0)
            __hip_atomic_fetch_add(ctr + bslot, 1u, __ATOMIC_RELAXED, __HIP_MEMORY_SCOPE_AGENT);

        // off-critical-path: store io[t-1] = v (output of previous step)
        float* outP = io + (size_t)(t - 1) * (BA * HD);
#pragma unroll
        for (int r = 0; r < 4; ++r)
            outP[(size_t)(brow + r) * HD + col] = v[r];

        // off-critical-path: prefetch xw[t+1]
        float xwn[4] = {0.f, 0.f, 0.f, 0.f};
        if (t + 1 < SQ) {
            const float* nxt = io + (size_t)(t + 1) * (BA * HD);
#pragma unroll
            for (int r = 0; r < 4; ++r)
                xwn[r] = nxt[(size_t)(brow + r) * HD + col];
        }

        if (tid == 0) {
            const unsigned target = (unsigned)(NWG) * (unsigned)t;
            unsigned s;
            do {
                s = 0;
#pragma unroll
                for (int c = 0; c < NCTR; ++c)
                    s += __hip_atomic_load(ctr + c * CTR_STRIDE,
                                           __ATOMIC_RELAXED, __HIP_MEMORY_SCOPE_AGENT);
            } while (s < target);
        }
        __syncthreads();

        const unsigned short* Ph = (t & 1) ? H0 : H1;  // produced at step t-1
        unsigned short*       Nh = (t & 1) ? H1 : H0;  // produced at step t

        const unsigned short* ap = Ph + (size_t)ab * HD + kf;

        f32x4 acc = {};
#pragma unroll 8
        for (int kc = 0; kc < 32; ++kc) {
            short8 Af = ld_frag(ap + kc * 32);
            short8 Bh = *(const short8*)&Whi[rf][kc * 32 + kf];
            short8 Bl = *(const short8*)&Wlo[rf][kc * 32 + kf];
            acc = __builtin_amdgcn_mfma_f32_16x16x32_bf16(Af, Bh, acc, 0, 0, 0);
            acc = __builtin_amdgcn_mfma_f32_16x16x32_bf16(Af, Bl, acc, 0, 0, 0);
        }

#pragma unroll
        for (int r = 0; r < 4; ++r) {
            v[r] = tanhf(acc[r] + xwv[r]);
            hi4[r] = f2bf(v[r]);
            xwv[r] = xwn[r];
        }
#pragma unroll
        for (int r = 0; r < 4; ++r) {
            const unsigned oh = __shfl_xor(hi4[r], 1);
            if ((lane & 1) == 0) {
                const size_t e = ((size_t)(brow + r) * HD + col) >> 1;
                __hip_atomic_store((unsigned*)Nh + e, (hi4[r] & 0xffffu) | (oh << 16),
                                   __ATOMIC_RELAXED, __HIP_MEMORY_SCOPE_AGENT);
            }
        }
    }

    // epilogue: io[511] and h_n
    float* outL = io + (size_t)(SQ - 1) * (BA * HD);
#pragma unroll
    for (int r = 0; r < 4; ++r) {
        const size_t o = (size_t)(brow + r) * HD + col;
        outL[o] = v[r];
        hn[o]   = v[r];
    }
}

// =====================================================================
extern "C" void kernel_launch(void* const* d_in, const int* in_sizes, int n_in,
                              void* d_out, int out_size, void* d_ws, size_t ws_size,
                              hipStream_t stream) {
    const float* x   = (const float*)d_in[0];
    const float* Wih = (const float*)d_in[1];
    const float* Whh = (const float*)d_in[2];
    const float* bih = (const float*)d_in[3];
    const float* bhh = (const float*)d_in[4];

    float* io = (float*)d_out;                       // [512][64][1024]
    float* hn = io + (size_t)SQ * BA * HD;           // [1][64][1024]

    unsigned* ctr = (unsigned*)d_ws;                              // 8 lines x 256 B
    unsigned short* hbuf = (unsigned short*)((char*)d_ws + 4096); // 256 KB ping-pong

    hipLaunchKernelGGL(xw_gemm, dim3(256, 8), dim3(256), 0, stream,
                       x, Wih, bih, bhh, io, ctr);

    void* args[] = {(void*)&Whh, (void*)&io, (void*)&hn, (void*)&hbuf, (void*)&ctr};
    hipLaunchCooperativeKernel((void*)rnn_recurrence, dim3(NWG), dim3(256),
                               args, 0, stream);
}